// Round 1
// baseline (155.421 us; speedup 1.0000x reference)
//
#include <hip/hip_runtime.h>
#include <math.h>

// Problem constants (from reference setup_inputs)
#define B 16
#define S 4096
#define H 16
#define D 128
#define P 32768

#define NSPLIT 8
#define WAVES_PER_BLOCK 4
#define TOK_PER_BLOCK (S / NSPLIT)                      // 512
#define TOK_PER_WAVE (TOK_PER_BLOCK / WAVES_PER_BLOCK)  // 128

// Kernel 1: flash-decode partials. grid = (NSPLIT, H, B), block = 256.
// Each wave processes TOK_PER_WAVE tokens with online softmax; the 4 waves
// of a block are combined through LDS; un-normalized partial (acc[D], m, l)
// is written to ws at [(b*H+h)*NSPLIT + split]*(D+2).
__global__ __launch_bounds__(256) void pa_partial(
    const float* __restrict__ q,
    const float* __restrict__ kv,
    const int* __restrict__ kidx,
    const int* __restrict__ vidx,
    float* __restrict__ ws)
{
    const int split = blockIdx.x;
    const int h     = blockIdx.y;
    const int b     = blockIdx.z;
    const int wave  = threadIdx.x >> 6;
    const int lane  = threadIdx.x & 63;

    const float scale = 0.08838834764831845f;  // 1/sqrt(128)

    const float* kbase = kv;                       // [P][H][D]
    const float* vbase = kv + (size_t)P * H * D;   // [P][H][D]

    // q fragment: 2 consecutive floats per lane (64*2 = 128 = D)
    const float2 qv = *reinterpret_cast<const float2*>(
        q + ((size_t)b * H + h) * D + lane * 2);

    float  m   = -INFINITY;
    float  l   = 0.f;
    float2 acc = make_float2(0.f, 0.f);

    const int s0 = split * TOK_PER_BLOCK + wave * TOK_PER_WAVE;

    for (int half = 0; half < TOK_PER_WAVE / 64; ++half) {
        const int sbase = s0 + half * 64;
        // one index per lane, broadcast below via shfl
        const int myk = kidx[(size_t)b * S + sbase + lane];
        const int myv = vidx[(size_t)b * S + sbase + lane];

        #pragma unroll 4
        for (int t = 0; t < 64; ++t) {
            const int kp = __shfl(myk, t);
            const int vp = __shfl(myv, t);

            const float2 kvv = *reinterpret_cast<const float2*>(
                kbase + ((size_t)kp * H + h) * D + lane * 2);
            const float2 vvv = *reinterpret_cast<const float2*>(
                vbase + ((size_t)vp * H + h) * D + lane * 2);

            float partial = qv.x * kvv.x + qv.y * kvv.y;
            // 64-lane butterfly reduce -> every lane holds the full dot
            #pragma unroll
            for (int off = 32; off > 0; off >>= 1)
                partial += __shfl_xor(partial, off);

            const float score = partial * scale;
            const float mnew  = fmaxf(m, score);
            const float alpha = __expf(m - mnew);
            const float p     = __expf(score - mnew);
            l     = l * alpha + p;
            acc.x = acc.x * alpha + p * vvv.x;
            acc.y = acc.y * alpha + p * vvv.y;
            m     = mnew;
        }
    }

    // combine the 4 waves of this block via LDS
    __shared__ float lds_m[WAVES_PER_BLOCK];
    __shared__ float lds_l[WAVES_PER_BLOCK];
    __shared__ float lds_acc[WAVES_PER_BLOCK][D];

    lds_acc[wave][lane * 2]     = acc.x;
    lds_acc[wave][lane * 2 + 1] = acc.y;
    if (lane == 0) { lds_m[wave] = m; lds_l[wave] = l; }
    __syncthreads();

    float* out = ws + ((size_t)(b * H + h) * NSPLIT + split) * (D + 2);
    if (threadIdx.x < D) {
        const int d = threadIdx.x;
        const float M = fmaxf(fmaxf(lds_m[0], lds_m[1]),
                              fmaxf(lds_m[2], lds_m[3]));
        float L = 0.f, a = 0.f;
        #pragma unroll
        for (int w = 0; w < WAVES_PER_BLOCK; ++w) {
            const float e = __expf(lds_m[w] - M);
            L += lds_l[w] * e;
            a += lds_acc[w][d] * e;
        }
        out[d] = a;
        if (d == 0) { out[D] = M; out[D + 1] = L; }
    }
}

// Kernel 2: reduce NSPLIT partials per (b,h), normalize, write output.
// grid = B*H blocks, 128 threads (one per d).
__global__ __launch_bounds__(128) void pa_reduce(
    const float* __restrict__ ws, float* __restrict__ out)
{
    const int bh = blockIdx.x;      // b*H + h
    const int d  = threadIdx.x;
    const float* base = ws + (size_t)bh * NSPLIT * (D + 2);

    float M = -INFINITY;
    #pragma unroll
    for (int i = 0; i < NSPLIT; ++i)
        M = fmaxf(M, base[i * (D + 2) + D]);

    float L = 0.f, a = 0.f;
    #pragma unroll
    for (int i = 0; i < NSPLIT; ++i) {
        const float e = __expf(base[i * (D + 2) + D] - M);
        L += base[i * (D + 2) + D + 1] * e;
        a += base[i * (D + 2) + d] * e;
    }
    out[(size_t)bh * D + d] = a / L;
}

extern "C" void kernel_launch(void* const* d_in, const int* in_sizes, int n_in,
                              void* d_out, int out_size, void* d_ws, size_t ws_size,
                              hipStream_t stream) {
    const float* q    = (const float*)d_in[0];
    const float* kv   = (const float*)d_in[1];
    const int*   kidx = (const int*)d_in[2];
    const int*   vidx = (const int*)d_in[3];
    float*       out  = (float*)d_out;
    float*       ws   = (float*)d_ws;

    // ws usage: B*H*NSPLIT*(D+2)*4 bytes = 1,064,960 bytes
    dim3 grid1(NSPLIT, H, B);
    pa_partial<<<grid1, 256, 0, stream>>>(q, kv, kidx, vidx, ws);
    pa_reduce<<<B * H, 128, 0, stream>>>(ws, out);
}